// Round 1
// baseline (1858.206 us; speedup 1.0000x reference)
//
#include <hip/hip_runtime.h>
#include <math.h>

// Problem constants (from reference)
#define VSZ   50000
#define EDIM  256
#define HDIM  256
#define H2D   128
#define NCLS  12
#define NB    64
#define NL    512
#define G4    512      // 4*H2
#define NNC   1024     // gates for both directions
#define MM    32768    // NL*NB rows
#define START_TAG 10
#define STOP_TAG  11
#define IMPOSSIBLE -10000.0f

__device__ __forceinline__ float sigmoidf_(float x) {
    return 1.0f / (1.0f + expf(-x));
}

// ---------------------------------------------------------------------------
// K1/K3: gates_x = A @ [W_ih_f;W_ih_r]^T + (b_ih+b_hh)
// A: [rows][256] f32 (optionally gathered rows via gidx), out: [MM][1024]
// BM=128, BN=128, BK=32, 256 threads, 8x8 micro-tile.
// ---------------------------------------------------------------------------
template <bool GATHER>
__global__ __launch_bounds__(256)
void gemm_gates(const float* __restrict__ A,
                const int*   __restrict__ gidx,
                const float* __restrict__ wf,   // [512][256]
                const float* __restrict__ wr,   // [512][256]
                const float* __restrict__ bihf, const float* __restrict__ bhhf,
                const float* __restrict__ bihr, const float* __restrict__ bhhr,
                float* __restrict__ out)
{
    __shared__ __align__(16) float As[32][132];   // transposed A tile [k][m]
    __shared__ __align__(16) float Bs[32][132];   // transposed B tile [k][n]

    const int tid = threadIdx.x;
    const int n0  = blockIdx.x * 128;   // 0..896 (8 blocks)
    const int m0  = blockIdx.y * 128;   // 0..32640 (256 blocks)
    const int ty  = tid >> 4;           // 0..15
    const int tx  = tid & 15;           // 0..15

    float acc[8][8];
#pragma unroll
    for (int i = 0; i < 8; ++i)
#pragma unroll
        for (int j = 0; j < 8; ++j) acc[i][j] = 0.0f;

    const bool  fwdside = (n0 < 512);
    const float* wsrc   = fwdside ? wf : wr;
    const int    nbase  = fwdside ? n0 : (n0 - 512);

    // Hoist gather indices (row set per thread is kt-invariant)
    int srcA[4];
#pragma unroll
    for (int it = 0; it < 4; ++it) {
        int li  = tid + it * 256;
        int row = m0 + (li >> 3);
        srcA[it] = GATHER ? gidx[row] : row;
    }

    for (int kt = 0; kt < 8; ++kt) {
        // ---- stage A tile (128 rows x 32 k) ----
#pragma unroll
        for (int it = 0; it < 4; ++it) {
            int li = tid + it * 256;
            int r  = li >> 3;
            int c4 = li & 7;
            float4 v = ((const float4*)A)[(size_t)srcA[it] * 64 + kt * 8 + c4];
            As[c4 * 4 + 0][r] = v.x;
            As[c4 * 4 + 1][r] = v.y;
            As[c4 * 4 + 2][r] = v.z;
            As[c4 * 4 + 3][r] = v.w;
        }
        // ---- stage B tile (128 n-rows x 32 k) ----
#pragma unroll
        for (int it = 0; it < 4; ++it) {
            int li = tid + it * 256;
            int r  = li >> 3;
            int c4 = li & 7;
            float4 v = ((const float4*)wsrc)[(size_t)(nbase + r) * 64 + kt * 8 + c4];
            Bs[c4 * 4 + 0][r] = v.x;
            Bs[c4 * 4 + 1][r] = v.y;
            Bs[c4 * 4 + 2][r] = v.z;
            Bs[c4 * 4 + 3][r] = v.w;
        }
        __syncthreads();

#pragma unroll
        for (int k = 0; k < 32; ++k) {
            float a[8], b[8];
            *(float4*)&a[0] = *(const float4*)&As[k][ty * 8];
            *(float4*)&a[4] = *(const float4*)&As[k][ty * 8 + 4];
            *(float4*)&b[0] = *(const float4*)&Bs[k][tx * 8];
            *(float4*)&b[4] = *(const float4*)&Bs[k][tx * 8 + 4];
#pragma unroll
            for (int i = 0; i < 8; ++i)
#pragma unroll
                for (int j = 0; j < 8; ++j)
                    acc[i][j] = fmaf(a[i], b[j], acc[i][j]);
        }
        __syncthreads();
    }

    // bias per output column (b_ih + b_hh), then store
    float bias[8];
#pragma unroll
    for (int j = 0; j < 8; ++j) {
        int gn = n0 + tx * 8 + j;
        bias[j] = fwdside ? (bihf[gn] + bhhf[gn]) : (bihr[gn - 512] + bhhr[gn - 512]);
    }
#pragma unroll
    for (int i = 0; i < 8; ++i) {
        int m = m0 + ty * 8 + i;
        float4 s0, s1;
        s0.x = acc[i][0] + bias[0]; s0.y = acc[i][1] + bias[1];
        s0.z = acc[i][2] + bias[2]; s0.w = acc[i][3] + bias[3];
        s1.x = acc[i][4] + bias[4]; s1.y = acc[i][5] + bias[5];
        s1.z = acc[i][6] + bias[6]; s1.w = acc[i][7] + bias[7];
        float4* op = (float4*)(out + (size_t)m * NNC + n0 + tx * 8);
        op[0] = s0;
        op[1] = s1;
    }
}

// ---------------------------------------------------------------------------
// K2/K4: LSTM recurrence. 128 blocks = 64 batch slots x 2 directions.
// 512 threads; thread j owns gate j, W_hh row j in registers (128 VGPRs).
// h broadcast through LDS; c lives in registers of threads 0..127.
// out layout: out[m][0:128]=h_fwd, out[m][128:256]=h_rev  (m = t*64+bb)
// ---------------------------------------------------------------------------
__global__ __launch_bounds__(512, 2)
void lstm_rec(const float* __restrict__ gx,    // [MM][1024]
              const float* __restrict__ whf,   // [512][128]
              const float* __restrict__ whr,
              const float* __restrict__ h0,    // [2][64][128]
              const float* __restrict__ c0,
              float* __restrict__ out)         // [MM][256]
{
    __shared__ __align__(16) float h_lds[H2D];
    __shared__ __align__(16) float gates[G4];

    const int j   = threadIdx.x;
    const int dir = blockIdx.x >> 6;   // 0 fwd, 1 rev
    const int bb  = blockIdx.x & 63;
    const float* W = dir ? whr : whf;

    // W_hh row j -> registers
    float w[H2D];
#pragma unroll
    for (int k4 = 0; k4 < 32; ++k4) {
        float4 v = ((const float4*)W)[(size_t)j * 32 + k4];
        w[4 * k4 + 0] = v.x; w[4 * k4 + 1] = v.y;
        w[4 * k4 + 2] = v.z; w[4 * k4 + 3] = v.w;
    }

    float creg = 0.0f;
    if (j < H2D) {
        h_lds[j] = h0[dir * (NB * H2D) + bb * H2D + j];
        creg     = c0[dir * (NB * H2D) + bb * H2D + j];
    }
    __syncthreads();

    const int chunk = j >> 7;     // 0:i 1:f 2:g 3:o (wave-uniform)
    const float4* h4 = (const float4*)h_lds;

    for (int ti = 0; ti < NL; ++ti) {
        const int t = dir ? (NL - 1 - ti) : ti;
        const size_t m = (size_t)t * NB + bb;

        // issue input-gate load early; not needed until after the dot
        const float gxv = gx[m * NNC + dir * 512 + j];

        float dot = 0.0f;
#pragma unroll
        for (int k4 = 0; k4 < 32; ++k4) {
            float4 hv = h4[k4];                       // LDS broadcast
            dot = fmaf(w[4 * k4 + 0], hv.x, dot);
            dot = fmaf(w[4 * k4 + 1], hv.y, dot);
            dot = fmaf(w[4 * k4 + 2], hv.z, dot);
            dot = fmaf(w[4 * k4 + 3], hv.w, dot);
        }
        const float pre = dot + gxv;
        const float act = (chunk == 2) ? tanhf(pre) : sigmoidf_(pre);
        gates[j] = act;
        __syncthreads();

        if (j < H2D) {
            const float ig = gates[j];
            const float fg = gates[j + 128];
            const float gg = gates[j + 256];
            const float og = gates[j + 384];
            creg = fg * creg + ig * gg;
            const float hnew = og * tanhf(creg);
            h_lds[j] = hnew;
            out[m * HDIM + dir * H2D + j] = hnew;
        }
        __syncthreads();
    }
}

// ---------------------------------------------------------------------------
// K5: feats = out2 @ w_out^T + b_out   (M=32768, N=12, K=256)
// ---------------------------------------------------------------------------
__global__ __launch_bounds__(256)
void feats_kernel(const float* __restrict__ out2,
                  const float* __restrict__ w_out,   // [12][256]
                  const float* __restrict__ b_out,
                  float* __restrict__ feats)         // [MM][12]
{
    __shared__ __align__(16) float wl[NCLS * HDIM];
    const int tid = threadIdx.x;
#pragma unroll
    for (int i = 0; i < NCLS; ++i) wl[tid + i * 256] = w_out[tid + i * 256];
    __syncthreads();

    const int m = blockIdx.x * 256 + tid;
    float acc[NCLS];
#pragma unroll
    for (int c = 0; c < NCLS; ++c) acc[c] = 0.0f;

    const float4* x4 = (const float4*)out2 + (size_t)m * 64;
    const float4* w4 = (const float4*)wl;
    for (int k4 = 0; k4 < 64; ++k4) {
        float4 x = x4[k4];
#pragma unroll
        for (int c = 0; c < NCLS; ++c) {
            float4 wv = w4[c * 64 + k4];              // LDS broadcast
            acc[c] = fmaf(x.x, wv.x, acc[c]);
            acc[c] = fmaf(x.y, wv.y, acc[c]);
            acc[c] = fmaf(x.z, wv.z, acc[c]);
            acc[c] = fmaf(x.w, wv.w, acc[c]);
        }
    }
#pragma unroll
    for (int c = 0; c < NCLS; ++c)
        feats[(size_t)m * NCLS + c] = acc[c] + b_out[c];
}

// ---------------------------------------------------------------------------
// K6: Viterbi forward. One block (one wave) per batch slot b.
// emit[t][b][i] = feats[b*512 + t]  (flat-order identity, see analysis)
// ---------------------------------------------------------------------------
__global__ __launch_bounds__(64)
void viterbi_fwd(const float* __restrict__ feats,
                 const float* __restrict__ masks,   // [B][L]
                 const float* __restrict__ trans,   // [12][12]
                 float* __restrict__ best_score,    // d_out[0:64]
                 unsigned char* __restrict__ bps,   // [L][B][12]
                 int* __restrict__ best_tag)        // ws
{
    const int b    = blockIdx.x;
    const int lane = threadIdx.x;

    float tr[NCLS];
#pragma unroll
    for (int jj = 0; jj < NCLS; ++jj)
        tr[jj] = (lane < NCLS) ? trans[lane * NCLS + jj] : 0.0f;

    float msv = (lane == START_TAG) ? 0.0f : IMPOSSIBLE;

    for (int t = 0; t < NL; ++t) {
        const float emit = (lane < NCLS) ? feats[((size_t)b * NL + t) * NCLS + lane] : 0.0f;
        const float mt   = masks[b * NL + t];

        float best = -3.4e38f;
        int   bj   = 0;
#pragma unroll
        for (int jj = 0; jj < NCLS; ++jj) {
            float msj = __shfl(msv, jj);
            float v   = msj + tr[jj];
            if (v > best) { best = v; bj = jj; }   // strict > keeps first max (argmax)
        }
        const float sc = best + emit;
        msv = mt * sc + (1.0f - mt) * msv;
        if (lane < NCLS)
            bps[((size_t)t * NB + b) * NCLS + lane] = (unsigned char)bj;
    }

    const float fin = (lane < NCLS) ? (msv + trans[STOP_TAG * NCLS + lane]) : -3.4e38f;
    float bv = -3.4e38f;
    int   bt = 0;
#pragma unroll
    for (int jj = 0; jj < NCLS; ++jj) {
        float v = __shfl(fin, jj);
        if (v > bv) { bv = v; bt = jj; }
    }
    if (lane == 0) {
        best_score[b] = bv;
        best_tag[b]   = bt;
    }
}

// ---------------------------------------------------------------------------
// K7: backtrace. Thread b walks its chain. path written as float.
// ---------------------------------------------------------------------------
__global__ __launch_bounds__(64)
void backtrace(const unsigned char* __restrict__ bps,
               const int* __restrict__ best_tag,
               const float* __restrict__ masks,
               float* __restrict__ path_out)        // d_out + 64, [B][L]
{
    const int b = threadIdx.x;
    float s = 0.0f;
    for (int t = 0; t < NL; ++t) s += masks[b * NL + t];
    const int len  = (int)(s + 0.5f);
    const int btag = best_tag[b];

    int cur = btag;
    for (int t = NL - 1; t >= 0; --t) {
        const int tb  = (t == NL - 1) ? (NL - 1) : (t + 1);   // bps_next[t]
        const int nxt = bps[((size_t)tb * NB + b) * NCLS + cur];
        const int val = (t >= len - 1) ? btag : nxt;
        cur = val;
        path_out[(size_t)b * NL + t] = (t < len) ? (float)val : 0.0f;
    }
}

// ---------------------------------------------------------------------------
extern "C" void kernel_launch(void* const* d_in, const int* in_sizes, int n_in,
                              void* d_out, int out_size, void* d_ws, size_t ws_size,
                              hipStream_t stream)
{
    const int*   sentence = (const int*)  d_in[0];
    const float* masks    = (const float*)d_in[1];
    const float* emb      = (const float*)d_in[2];
    const float* w_ih_f1  = (const float*)d_in[3];
    const float* w_hh_f1  = (const float*)d_in[4];
    const float* b_ih_f1  = (const float*)d_in[5];
    const float* b_hh_f1  = (const float*)d_in[6];
    const float* w_ih_r1  = (const float*)d_in[7];
    const float* w_hh_r1  = (const float*)d_in[8];
    const float* b_ih_r1  = (const float*)d_in[9];
    const float* b_hh_r1  = (const float*)d_in[10];
    const float* w_ih_f2  = (const float*)d_in[11];
    const float* w_hh_f2  = (const float*)d_in[12];
    const float* b_ih_f2  = (const float*)d_in[13];
    const float* b_hh_f2  = (const float*)d_in[14];
    const float* w_ih_r2  = (const float*)d_in[15];
    const float* w_hh_r2  = (const float*)d_in[16];
    const float* b_ih_r2  = (const float*)d_in[17];
    const float* b_hh_r2  = (const float*)d_in[18];
    const float* w_out    = (const float*)d_in[19];
    const float* b_out    = (const float*)d_in[20];
    const float* trans    = (const float*)d_in[21];
    const float* h0_1     = (const float*)d_in[22];
    const float* c0_1     = (const float*)d_in[23];
    const float* h0_2     = (const float*)d_in[24];
    const float* c0_2     = (const float*)d_in[25];

    // workspace layout (f32 unless noted); gx reused between layers
    float* gx    = (float*)d_ws;                       // [32768][1024]  134.2 MB
    float* out1  = gx   + (size_t)MM * NNC;            // [32768][256]    33.6 MB
    float* out2  = out1 + (size_t)MM * HDIM;           // [32768][256]    33.6 MB
    float* feats = out2 + (size_t)MM * HDIM;           // [32768][12]      1.6 MB
    int*   btag  = (int*)(feats + (size_t)MM * NCLS);  // [64]
    unsigned char* bps = (unsigned char*)(btag + 64);  // [512][64][12]  384 KB

    dim3 gemm_grid(NNC / 128, MM / 128);   // (8, 256)

    // Layer 1: input gates (gathered through sentence) -> recurrence
    gemm_gates<true><<<gemm_grid, 256, 0, stream>>>(
        emb, sentence, w_ih_f1, w_ih_r1, b_ih_f1, b_hh_f1, b_ih_r1, b_hh_r1, gx);
    lstm_rec<<<128, 512, 0, stream>>>(gx, w_hh_f1, w_hh_r1, h0_1, c0_1, out1);

    // Layer 2
    gemm_gates<false><<<gemm_grid, 256, 0, stream>>>(
        out1, nullptr, w_ih_f2, w_ih_r2, b_ih_f2, b_hh_f2, b_ih_r2, b_hh_r2, gx);
    lstm_rec<<<128, 512, 0, stream>>>(gx, w_hh_f2, w_hh_r2, h0_2, c0_2, out2);

    // Projection + CRF
    feats_kernel<<<MM / 256, 256, 0, stream>>>(out2, w_out, b_out, feats);
    viterbi_fwd<<<NB, 64, 0, stream>>>(feats, masks, trans, (float*)d_out, bps, btag);
    backtrace<<<1, 64, 0, stream>>>(bps, btag, masks, (float*)d_out + 64);
}